// Round 5
// baseline (801.994 us; speedup 1.0000x reference)
//
#include <hip/hip_runtime.h>
#include <hip/hip_bf16.h>
#include <math.h>

#define NNODES 50000
#define NEDGES 800000
#define DIN 768
#define DH 256
#define NCLS 4
#define NGRAPHS 64
#define SCAN_BLOCKS 196   // ceil(NNODES/256)

typedef __bf16 bf16x8 __attribute__((ext_vector_type(8)));
typedef float f32x4 __attribute__((ext_vector_type(4)));

static __device__ __forceinline__ float bf2f(unsigned short u) {
    union { unsigned u32; float f; } v; v.u32 = ((unsigned)u) << 16; return v.f;
}
static __device__ __forceinline__ unsigned short f2bf(float f) {
    union { float f; unsigned u; } v; v.f = f;
    unsigned r = (v.u + 0x7fffu + ((v.u >> 16) & 1u)) >> 16;
    return (unsigned short)r;
}
static __device__ __forceinline__ void unpack8(uint4 u, float* f) {
    f[0] = bf2f((unsigned short)(u.x & 0xffff)); f[1] = bf2f((unsigned short)(u.x >> 16));
    f[2] = bf2f((unsigned short)(u.y & 0xffff)); f[3] = bf2f((unsigned short)(u.y >> 16));
    f[4] = bf2f((unsigned short)(u.z & 0xffff)); f[5] = bf2f((unsigned short)(u.z >> 16));
    f[6] = bf2f((unsigned short)(u.w & 0xffff)); f[7] = bf2f((unsigned short)(u.w >> 16));
}

// ---------------- dtype detection (fp32 vs bf16 inputs) ----------------
__global__ void detect_dtype(const unsigned short* __restrict__ x, int* __restrict__ flag) {
    __shared__ int cnt_s;
    if (threadIdx.x == 0) cnt_s = 0;
    __syncthreads();
    int c = 0;
    for (int i = 0; i < 16; ++i) {
        float v = bf2f(x[threadIdx.x * 16 + i]);
        if (!(fabsf(v) < 1e10f)) c++;
    }
    atomicAdd(&cnt_s, c);
    __syncthreads();
    if (threadIdx.x == 0) flag[0] = (cnt_s > 32) ? 1 : 0;  // 1 => fp32
}

static __device__ __forceinline__ unsigned short cload(const void* src, int i, int fp32) {
    return fp32 ? f2bf(((const float*)src)[i]) : ((const unsigned short*)src)[i];
}

// ---------------- fused small-weight canonicalization ----------------
__global__ void canon_small(const void* b_in, const void* convB, const void* lnG,
                            const void* lnB, const void* W1, const void* W2,
                            const void* b1, const void* b2,
                            unsigned short* __restrict__ dst, const int* __restrict__ flag) {
    int i = blockIdx.x * 256 + threadIdx.x;
    if (i >= 69380) return;
    const int fp32 = flag[0];
    int j = i;
    if (j < 256)  { dst[i] = cload(b_in, j, fp32); return; }  j -= 256;
    if (j < 768)  { dst[i] = cload(convB, j, fp32); return; } j -= 768;
    if (j < 768)  { dst[i] = cload(lnG, j, fp32); return; }   j -= 768;
    if (j < 768)  { dst[i] = cload(lnB, j, fp32); return; }   j -= 768;
    if (j < 65536){ dst[i] = cload(W1, j, fp32); return; }    j -= 65536;
    if (j < 1024) { dst[i] = cload(W2, j, fp32); return; }    j -= 1024;
    if (j < 256)  { dst[i] = cload(b1, j, fp32); return; }    j -= 256;
    dst[i] = cload(b2, j, fp32);
}

// ---------------- fused convert+transpose for GEMM B operands ----------------
__global__ void transpose_win(const void* __restrict__ src, unsigned short* __restrict__ dst,
                              const int* __restrict__ flag) {
    int idx = blockIdx.x * 256 + threadIdx.x;
    if (idx < DIN * DH) {
        int r = idx / DH, c = idx % DH;
        dst[(size_t)c * DIN + r] = cload(src, idx, flag[0]);
    }
}
__global__ void transpose_convw(const void* __restrict__ src, unsigned short* __restrict__ dst,
                                const int* __restrict__ flag) {
    int idx = blockIdx.x * 256 + threadIdx.x;
    if (idx < 3 * DH * DH) {
        int l = idx >> 16, rc = idx & 65535;
        int r = rc >> 8, c = rc & 255;
        dst[(l << 16) + c * DH + r] = cload(src, idx, flag[0]);
    }
}

// ---------------- diagnostic sentinel (ws too small) ----------------
__global__ void fill_sentinel(float* out, int n) {
    int i = blockIdx.x * 256 + threadIdx.x;
    if (i < n) out[i] = 1000.0f;
}

// ---------------- CSR build ----------------
__global__ void count_edges(const int* __restrict__ ei, int* __restrict__ cnt) {
    int e = blockIdx.x * 256 + threadIdx.x;
    if (e < NEDGES) atomicAdd(&cnt[ei[NEDGES + e]], 1);
}

__global__ void scan_local(const int* __restrict__ cnt, int* __restrict__ rowptr,
                           int* __restrict__ bsum) {
    __shared__ int tmp[256];
    int i = blockIdx.x * 256 + threadIdx.x;
    int v = (i < NNODES) ? cnt[i] : 0;
    tmp[threadIdx.x] = v;
    __syncthreads();
    for (int off = 1; off < 256; off <<= 1) {
        int a = (threadIdx.x >= off) ? tmp[threadIdx.x - off] : 0;
        __syncthreads();
        tmp[threadIdx.x] += a;
        __syncthreads();
    }
    if (i < NNODES) rowptr[i] = tmp[threadIdx.x] - v;  // local exclusive
    if (threadIdx.x == 255) bsum[blockIdx.x] = tmp[255];
}
__global__ void scan_bsum(const int* __restrict__ bsum, int* __restrict__ boff) {
    __shared__ int tmp[256];
    int t = threadIdx.x;
    int v = (t < SCAN_BLOCKS) ? bsum[t] : 0;
    tmp[t] = v;
    __syncthreads();
    for (int off = 1; off < 256; off <<= 1) {
        int a = (t >= off) ? tmp[t - off] : 0;
        __syncthreads();
        tmp[t] += a;
        __syncthreads();
    }
    if (t < SCAN_BLOCKS) boff[t] = tmp[t] - v;
}
__global__ void scan_finish(int* __restrict__ rowptr, const int* __restrict__ boff,
                            const int* __restrict__ cnt, float* __restrict__ dinv) {
    int i = blockIdx.x * 256 + threadIdx.x;
    if (i < NNODES) {
        rowptr[i] += boff[blockIdx.x];
        dinv[i] = rsqrtf((float)(1 + cnt[i]));  // +1 self-loop
    }
    if (i == 0) rowptr[NNODES] = NEDGES;
}

__global__ void fill_csr(const int* __restrict__ ei, const int* __restrict__ rowptr,
                         int* __restrict__ cursor, int* __restrict__ csrc) {
    int e = blockIdx.x * 256 + threadIdx.x;
    if (e < NEDGES) {
        int s = ei[e];
        int d = ei[NEDGES + e];
        int pos = rowptr[d] + atomicAdd(&cursor[d], 1);
        csrc[pos] = s;
    }
}

// ---- GEMM: C[M,N]=A[M,K]@B[K,N], Bt=[N,K]; double-buffered LDS + reg prefetch ----
#define BM 128
#define BN 128
#define BK 32
#define LDSS 40

__global__ __launch_bounds__(256) void gemm_bf16_tn(
    const void* __restrict__ Araw, const int* __restrict__ dflag, int use_flag,
    const unsigned short* __restrict__ Bt, const unsigned short* __restrict__ bias,
    unsigned short* __restrict__ C, int M, int N, int K)
{
    __shared__ unsigned short As[2][BM * LDSS];
    __shared__ unsigned short Bs[2][BN * LDSS];
    const int a_fp32 = use_flag ? dflag[0] : 0;
    const int m0 = blockIdx.x * BM;
    const int n0 = blockIdx.y * BN;
    const int t = threadIdx.x;
    const int wave = t >> 6, lane = t & 63;
    const int quad = lane >> 4, l16 = lane & 15;
    const int wm = (wave >> 1) << 6;
    const int wn = (wave & 1) << 6;
    const int lrow = t >> 2;   // 0..63
    const int lcg = t & 3;     // 8-short column group

    f32x4 acc[4][4];
#pragma unroll
    for (int i = 0; i < 4; i++)
#pragma unroll
        for (int j = 0; j < 4; j++) acc[i][j] = (f32x4){0.f, 0.f, 0.f, 0.f};

    // prefetch registers
    float fA[16];
    uint4 uA[2];
    uint4 uB[2];

    auto loadTile = [&](int k0) {
#pragma unroll
        for (int p = 0; p < 2; ++p) {
            const int row = lrow + p * 64;
            const int gm = m0 + row;
            if (a_fp32) {
                if (gm < M) {
                    const float* Af = (const float*)Araw + (size_t)gm * K + k0 + lcg * 8;
                    float4 f0 = *(const float4*)Af;
                    float4 f1 = *(const float4*)(Af + 4);
                    fA[p * 8 + 0] = f0.x; fA[p * 8 + 1] = f0.y;
                    fA[p * 8 + 2] = f0.z; fA[p * 8 + 3] = f0.w;
                    fA[p * 8 + 4] = f1.x; fA[p * 8 + 5] = f1.y;
                    fA[p * 8 + 6] = f1.z; fA[p * 8 + 7] = f1.w;
                } else {
#pragma unroll
                    for (int j = 0; j < 8; j++) fA[p * 8 + j] = 0.f;
                }
            } else {
                uA[p] = (gm < M)
                    ? *(const uint4*)((const unsigned short*)Araw + (size_t)gm * K + k0 + lcg * 8)
                    : make_uint4(0u, 0u, 0u, 0u);
            }
            const int gn = n0 + row;  // N==256: always in range
            uB[p] = *(const uint4*)(Bt + (size_t)gn * K + k0 + lcg * 8);
        }
    };
    auto storeTile = [&](int buf) {
#pragma unroll
        for (int p = 0; p < 2; ++p) {
            const int row = lrow + p * 64;
            uint4 av;
            if (a_fp32) {
                av.x = (unsigned)f2bf(fA[p * 8 + 0]) | ((unsigned)f2bf(fA[p * 8 + 1]) << 16);
                av.y = (unsigned)f2bf(fA[p * 8 + 2]) | ((unsigned)f2bf(fA[p * 8 + 3]) << 16);
                av.z = (unsigned)f2bf(fA[p * 8 + 4]) | ((unsigned)f2bf(fA[p * 8 + 5]) << 16);
                av.w = (unsigned)f2bf(fA[p * 8 + 6]) | ((unsigned)f2bf(fA[p * 8 + 7]) << 16);
            } else {
                av = uA[p];
            }
            *(uint4*)(&As[buf][row * LDSS + lcg * 8]) = av;
            *(uint4*)(&Bs[buf][row * LDSS + lcg * 8]) = uB[p];
        }
    };

    loadTile(0);
    storeTile(0);
    __syncthreads();
    int buf = 0;
    for (int k0 = 0; k0 < K; k0 += BK) {
        const bool more = (k0 + BK) < K;
        if (more) loadTile(k0 + BK);  // prefetch issues; results used only in storeTile
        bf16x8 af[4], bfv[4];
#pragma unroll
        for (int i = 0; i < 4; i++)
            af[i] = *(const bf16x8*)(&As[buf][(wm + 16 * i + l16) * LDSS + quad * 8]);
#pragma unroll
        for (int j = 0; j < 4; j++)
            bfv[j] = *(const bf16x8*)(&Bs[buf][(wn + 16 * j + l16) * LDSS + quad * 8]);
#pragma unroll
        for (int i = 0; i < 4; i++)
#pragma unroll
            for (int j = 0; j < 4; j++)
                acc[i][j] = __builtin_amdgcn_mfma_f32_16x16x32_bf16(af[i], bfv[j], acc[i][j], 0, 0, 0);
        if (more) {
            storeTile(buf ^ 1);  // vmcnt wait lands here, after the MFMA phase
            __syncthreads();
            buf ^= 1;
        }
    }
#pragma unroll
    for (int i = 0; i < 4; i++) {
#pragma unroll
        for (int j = 0; j < 4; j++) {
            int gc = n0 + wn + 16 * j + l16;
            float bv = bias ? bf2f(bias[gc]) : 0.f;
#pragma unroll
            for (int r = 0; r < 4; r++) {
                int gr = m0 + wm + 16 * i + quad * 4 + r;
                if (gr < M) C[(size_t)gr * N + gc] = f2bf(acc[i][j][r] + bv);
            }
        }
    }
}

// ------- fused: CSR gather + self-loop + bias + residual + ReLU + LayerNorm -------
// 2 nodes per wave; 1-deep neighbor lookahead to hide L2 gather latency.
__global__ __launch_bounds__(256) void aggregate_ln(
    const int* __restrict__ rowptr, const int* __restrict__ csrc,
    const float* __restrict__ dinv, const unsigned short* __restrict__ m,
    const unsigned short* __restrict__ convB,
    const unsigned short* __restrict__ lnG, const unsigned short* __restrict__ lnB,
    unsigned short* __restrict__ h)
{
    const int half = threadIdx.x >> 5;
    const int lane = threadIdx.x & 31;
    const int node = blockIdx.x * 8 + half;  // NNODES % 8 == 0
    const float di = dinv[node];
    const size_t base = (size_t)node * DH + lane * 8;

    float v[8];
    unpack8(*(const uint4*)(m + base), v);
    const float selfn = di * di;
#pragma unroll
    for (int j = 0; j < 8; j++) v[j] *= selfn;

    const int kb = rowptr[node], ke = rowptr[node + 1];
    int k = kb;
    uint4 cur = make_uint4(0u, 0u, 0u, 0u);
    float nrmC = 0.f;
    if (k < ke) {
        int s = csrc[k];
        cur = *(const uint4*)(m + (size_t)s * DH + lane * 8);
        nrmC = dinv[s] * di;
    }
    while (k < ke) {
        const int kn = k + 1;
        uint4 nxt = make_uint4(0u, 0u, 0u, 0u);
        float nrmN = 0.f;
        if (kn < ke) {
            int s = csrc[kn];
            nxt = *(const uint4*)(m + (size_t)s * DH + lane * 8);  // issued before cur consumed
            nrmN = dinv[s] * di;
        }
        float mv[8];
        unpack8(cur, mv);
#pragma unroll
        for (int j = 0; j < 8; j++) v[j] += mv[j] * nrmC;
        cur = nxt; nrmC = nrmN; k = kn;
    }

    float hv[8], cv[8];
    unpack8(*(const uint4*)(h + base), hv);
    unpack8(*(const uint4*)(convB + lane * 8), cv);
    float s1 = 0.f, s2 = 0.f;
#pragma unroll
    for (int j = 0; j < 8; j++) {
        v[j] = fmaxf(v[j] + cv[j] + hv[j], 0.f);
        s1 += v[j];
        s2 += v[j] * v[j];
    }
#pragma unroll
    for (int off = 16; off > 0; off >>= 1) {
        s1 += __shfl_xor(s1, off, 32);
        s2 += __shfl_xor(s2, off, 32);
    }
    const float mu = s1 * (1.f / 256.f);
    const float var = s2 * (1.f / 256.f) - mu * mu;
    const float rs = rsqrtf(var + 1e-5f);
    float gv[8], bv[8];
    unpack8(*(const uint4*)(lnG + lane * 8), gv);
    unpack8(*(const uint4*)(lnB + lane * 8), bv);
    unsigned short o[8];
#pragma unroll
    for (int j = 0; j < 8; j++) o[j] = f2bf((v[j] - mu) * rs * gv[j] + bv[j]);
    uint4 outp;
    outp.x = (unsigned)o[0] | ((unsigned)o[1] << 16);
    outp.y = (unsigned)o[2] | ((unsigned)o[3] << 16);
    outp.z = (unsigned)o[4] | ((unsigned)o[5] << 16);
    outp.w = (unsigned)o[6] | ((unsigned)o[7] << 16);
    *(uint4*)(h + base) = outp;
}

// ---------------- pooling: batch sorted -> boundary detection, no atomics ----------------
__global__ void find_bounds(const int* __restrict__ batch, int* __restrict__ s) {
    int i = blockIdx.x * 256 + threadIdx.x;
    if (i >= NNODES) return;
    int b = batch[i];
    int bp = (i == 0) ? -1 : batch[i - 1];
    for (int g = bp + 1; g <= b; ++g) s[g] = i;
    if (i == NNODES - 1)
        for (int g = b + 1; g <= NGRAPHS; ++g) s[g] = NNODES;
}

#define PSPLIT 8
__global__ __launch_bounds__(256) void pool_partial(
    const unsigned short* __restrict__ h, const int* __restrict__ s,
    float* __restrict__ pg)
{
    const int b = blockIdx.x >> 3, split = blockIdx.x & 7, f = threadIdx.x;
    const int i0 = s[b], i1 = s[b + 1];
    const int len = i1 - i0;
    const int c0 = i0 + (int)(((long)len * split) >> 3);
    const int c1 = i0 + (int)(((long)len * (split + 1)) >> 3);
    float mx = -INFINITY;
    for (int i = c0; i < c1; ++i) mx = fmaxf(mx, bf2f(h[(size_t)i * DH + f]));
    pg[(size_t)blockIdx.x * DH + f] = mx;
}
__global__ __launch_bounds__(256) void pool_reduce(const float* __restrict__ pg,
                                                   float* __restrict__ g) {
    const int b = blockIdx.x, f = threadIdx.x;
    float mx = -INFINITY;
#pragma unroll
    for (int j = 0; j < PSPLIT; ++j) mx = fmaxf(mx, pg[(size_t)(b * PSPLIT + j) * DH + f]);
    g[b * DH + f] = mx;
}

// ---------------- classifier: out = relu(g@W1+b1)@W2+b2 ----------------
__global__ __launch_bounds__(256) void classifier(
    const float* __restrict__ g, const unsigned short* __restrict__ W1,
    const unsigned short* __restrict__ b1, const unsigned short* __restrict__ W2,
    const unsigned short* __restrict__ b2, void* __restrict__ outv,
    const int* __restrict__ flag)
{
    __shared__ float gz[DH];
    __shared__ float zz[DH];
    const int b = blockIdx.x, t = threadIdx.x;
    gz[t] = g[b * DH + t];
    __syncthreads();
    float s = bf2f(b1[t]);
    for (int k = 0; k < DH; ++k) s += gz[k] * bf2f(W1[k * DH + t]);
    zz[t] = fmaxf(s, 0.f);
    __syncthreads();
    if (t < NCLS) {
        float s2 = bf2f(b2[t]);
        for (int k = 0; k < DH; ++k) s2 += zz[k] * bf2f(W2[k * NCLS + t]);
        if (flag[0]) ((float*)outv)[b * NCLS + t] = s2;
        else ((unsigned short*)outv)[b * NCLS + t] = f2bf(s2);
    }
}

extern "C" void kernel_launch(void* const* d_in, const int* in_sizes, int n_in,
                              void* d_out, int out_size, void* d_ws, size_t ws_size,
                              hipStream_t stream)
{
    const void* x      = d_in[0];
    const int* ei      = (const int*)d_in[1];
    const int* batch   = (const int*)d_in[2];
    const void* Win    = d_in[3];
    const void* b_in   = d_in[4];
    const void* convW  = d_in[5];
    const void* convB  = d_in[6];
    const void* lnG    = d_in[7];
    const void* lnB    = d_in[8];
    const void* W1     = d_in[9];
    const void* b1     = d_in[10];
    const void* W2     = d_in[11];
    const void* b2     = d_in[12];

    // workspace layout (bytes), 16B aligned
    char* ws = (char*)d_ws;
    unsigned short* h   = (unsigned short*)(ws + 0);          // 25,600,000
    unsigned short* m   = (unsigned short*)(ws + 25600000);   // 25,600,000
    int* csrc           = (int*)(ws + 51200000);              //  3,200,000
    int* rowptr         = (int*)(ws + 54400000);              //    200,016
    int* cnt            = (int*)(ws + 54600016);              //    200,000
    int* cursor         = (int*)(ws + 54800016);              //    200,000
    float* dinv         = (float*)(ws + 55000016);            //    200,000
    unsigned short* cw  = (unsigned short*)(ws + 55200016);   //    138,768
    unsigned short* WinT= (unsigned short*)(ws + 55338784);   //    393,216
    unsigned short* WcT = (unsigned short*)(ws + 55732000);   //    393,216
    float* g            = (float*)(ws + 56125216);            //     65,536
    float* pg           = (float*)(ws + 56190752);            //    524,288
    int* gb             = (int*)(ws + 56715040);              //        272
    int* bsum           = (int*)(ws + 56715312);              //        800
    int* boff           = (int*)(ws + 56716112);              //        800
    int* flag           = (int*)(ws + 56716912);              //         16
    const size_t NEED   = 56716928;
    if (ws_size < NEED) {
        fill_sentinel<<<(out_size / 2 + 255) / 256, 256, 0, stream>>>((float*)d_out, out_size / 2);
        return;
    }

    // canonical small weights (bf16 element offsets within cw)
    unsigned short* cBin   = cw + 0;
    unsigned short* cConvB = cw + 256;
    unsigned short* cLnG   = cw + 1024;
    unsigned short* cLnB   = cw + 1792;
    unsigned short* cW1    = cw + 2560;
    unsigned short* cW2    = cw + 68096;
    unsigned short* cB1    = cw + 69120;
    unsigned short* cB2    = cw + 69376;

    detect_dtype<<<1, 256, 0, stream>>>((const unsigned short*)x, flag);

    // ---- CSR build (dst-sorted) + degrees ----
    hipMemsetAsync(cnt, 0, 400000, stream);  // cnt AND cursor (contiguous)
    count_edges<<<(NEDGES + 255) / 256, 256, 0, stream>>>(ei, cnt);
    scan_local<<<SCAN_BLOCKS, 256, 0, stream>>>(cnt, rowptr, bsum);
    scan_bsum<<<1, 256, 0, stream>>>(bsum, boff);
    scan_finish<<<SCAN_BLOCKS, 256, 0, stream>>>(rowptr, boff, cnt, dinv);
    fill_csr<<<(NEDGES + 255) / 256, 256, 0, stream>>>(ei, rowptr, cursor, csrc);

    // ---- weights: canon + convert/transpose ----
    canon_small<<<(69380 + 255) / 256, 256, 0, stream>>>(b_in, convB, lnG, lnB, W1, W2, b1, b2, cw, flag);
    transpose_win<<<(DIN * DH + 255) / 256, 256, 0, stream>>>(Win, WinT, flag);
    transpose_convw<<<(3 * DH * DH + 255) / 256, 256, 0, stream>>>(convW, WcT, flag);

    // ---- h = x @ W_in + b_in ----
    dim3 gg((NNODES + BM - 1) / BM, DH / BN);
    gemm_bf16_tn<<<gg, 256, 0, stream>>>(x, flag, 1, WinT, cBin, h, NNODES, DH, DIN);

    // ---- 3 GCN layers ----
    for (int i = 0; i < 3; i++) {
        gemm_bf16_tn<<<gg, 256, 0, stream>>>(h, flag, 0, WcT + i * DH * DH, nullptr, m,
                                             NNODES, DH, DH);
        aggregate_ln<<<NNODES / 8, 256, 0, stream>>>(
            rowptr, csrc, dinv, m, cConvB + i * DH, cLnG + i * DH, cLnB + i * DH, h);
    }

    // ---- global max pool + classifier ----
    find_bounds<<<(NNODES + 255) / 256, 256, 0, stream>>>(batch, gb);
    pool_partial<<<NGRAPHS * PSPLIT, 256, 0, stream>>>(h, gb, pg);
    pool_reduce<<<NGRAPHS, 256, 0, stream>>>(pg, g);
    classifier<<<NGRAPHS, 256, 0, stream>>>(g, cW1, cB1, cW2, cB2, d_out, flag);
}

// Round 6
// 705.476 us; speedup vs baseline: 1.1368x; 1.1368x over previous
//
#include <hip/hip_runtime.h>
#include <hip/hip_bf16.h>
#include <math.h>

#define NNODES 50000
#define NEDGES 800000
#define DIN 768
#define DH 256
#define NCLS 4
#define NGRAPHS 64
#define SCAN_BLOCKS 196   // ceil(NNODES/256)

typedef __bf16 bf16x8 __attribute__((ext_vector_type(8)));
typedef float f32x4 __attribute__((ext_vector_type(4)));

static __device__ __forceinline__ float bf2f(unsigned short u) {
    union { unsigned u32; float f; } v; v.u32 = ((unsigned)u) << 16; return v.f;
}
static __device__ __forceinline__ unsigned short f2bf(float f) {
    union { float f; unsigned u; } v; v.f = f;
    unsigned r = (v.u + 0x7fffu + ((v.u >> 16) & 1u)) >> 16;
    return (unsigned short)r;
}
static __device__ __forceinline__ void unpack8(uint4 u, float* f) {
    f[0] = bf2f((unsigned short)(u.x & 0xffff)); f[1] = bf2f((unsigned short)(u.x >> 16));
    f[2] = bf2f((unsigned short)(u.y & 0xffff)); f[3] = bf2f((unsigned short)(u.y >> 16));
    f[4] = bf2f((unsigned short)(u.z & 0xffff)); f[5] = bf2f((unsigned short)(u.z >> 16));
    f[6] = bf2f((unsigned short)(u.w & 0xffff)); f[7] = bf2f((unsigned short)(u.w >> 16));
}

// ---------------- dtype detection (fp32 vs bf16 inputs) ----------------
__global__ void detect_dtype(const unsigned short* __restrict__ x, int* __restrict__ flag) {
    __shared__ int cnt_s;
    if (threadIdx.x == 0) cnt_s = 0;
    __syncthreads();
    int c = 0;
    for (int i = 0; i < 16; ++i) {
        float v = bf2f(x[threadIdx.x * 16 + i]);
        if (!(fabsf(v) < 1e10f)) c++;
    }
    atomicAdd(&cnt_s, c);
    __syncthreads();
    if (threadIdx.x == 0) flag[0] = (cnt_s > 32) ? 1 : 0;  // 1 => fp32
}

static __device__ __forceinline__ unsigned short cload(const void* src, int i, int fp32) {
    return fp32 ? f2bf(((const float*)src)[i]) : ((const unsigned short*)src)[i];
}

// ---------------- fused small-weight canonicalization ----------------
__global__ void canon_small(const void* b_in, const void* convB, const void* lnG,
                            const void* lnB, const void* W1, const void* W2,
                            const void* b1, const void* b2,
                            unsigned short* __restrict__ dst, const int* __restrict__ flag) {
    int i = blockIdx.x * 256 + threadIdx.x;
    if (i >= 69380) return;
    const int fp32 = flag[0];
    int j = i;
    if (j < 256)  { dst[i] = cload(b_in, j, fp32); return; }  j -= 256;
    if (j < 768)  { dst[i] = cload(convB, j, fp32); return; } j -= 768;
    if (j < 768)  { dst[i] = cload(lnG, j, fp32); return; }   j -= 768;
    if (j < 768)  { dst[i] = cload(lnB, j, fp32); return; }   j -= 768;
    if (j < 65536){ dst[i] = cload(W1, j, fp32); return; }    j -= 65536;
    if (j < 1024) { dst[i] = cload(W2, j, fp32); return; }    j -= 1024;
    if (j < 256)  { dst[i] = cload(b1, j, fp32); return; }    j -= 256;
    dst[i] = cload(b2, j, fp32);
}

// ---------------- fused convert+transpose for GEMM B operands ----------------
__global__ void transpose_win(const void* __restrict__ src, unsigned short* __restrict__ dst,
                              const int* __restrict__ flag) {
    int idx = blockIdx.x * 256 + threadIdx.x;
    if (idx < DIN * DH) {
        int r = idx / DH, c = idx % DH;
        dst[(size_t)c * DIN + r] = cload(src, idx, flag[0]);
    }
}
__global__ void transpose_convw(const void* __restrict__ src, unsigned short* __restrict__ dst,
                                const int* __restrict__ flag) {
    int idx = blockIdx.x * 256 + threadIdx.x;
    if (idx < 3 * DH * DH) {
        int l = idx >> 16, rc = idx & 65535;
        int r = rc >> 8, c = rc & 255;
        dst[(l << 16) + c * DH + r] = cload(src, idx, flag[0]);
    }
}

// ---------------- diagnostic sentinel (ws too small) ----------------
__global__ void fill_sentinel(float* out, int n) {
    int i = blockIdx.x * 256 + threadIdx.x;
    if (i < n) out[i] = 1000.0f;
}

// ---------------- CSR build ----------------
__global__ void count_edges(const int* __restrict__ ei, int* __restrict__ cnt) {
    int e = blockIdx.x * 256 + threadIdx.x;
    if (e < NEDGES) atomicAdd(&cnt[ei[NEDGES + e]], 1);
}

__global__ void scan_local(const int* __restrict__ cnt, int* __restrict__ rowptr,
                           int* __restrict__ bsum) {
    __shared__ int tmp[256];
    int i = blockIdx.x * 256 + threadIdx.x;
    int v = (i < NNODES) ? cnt[i] : 0;
    tmp[threadIdx.x] = v;
    __syncthreads();
    for (int off = 1; off < 256; off <<= 1) {
        int a = (threadIdx.x >= off) ? tmp[threadIdx.x - off] : 0;
        __syncthreads();
        tmp[threadIdx.x] += a;
        __syncthreads();
    }
    if (i < NNODES) rowptr[i] = tmp[threadIdx.x] - v;  // local exclusive
    if (threadIdx.x == 255) bsum[blockIdx.x] = tmp[255];
}
__global__ void scan_bsum(const int* __restrict__ bsum, int* __restrict__ boff) {
    __shared__ int tmp[256];
    int t = threadIdx.x;
    int v = (t < SCAN_BLOCKS) ? bsum[t] : 0;
    tmp[t] = v;
    __syncthreads();
    for (int off = 1; off < 256; off <<= 1) {
        int a = (t >= off) ? tmp[t - off] : 0;
        __syncthreads();
        tmp[t] += a;
        __syncthreads();
    }
    if (t < SCAN_BLOCKS) boff[t] = tmp[t] - v;
}
__global__ void scan_finish(int* __restrict__ rowptr, const int* __restrict__ boff,
                            const int* __restrict__ cnt, float* __restrict__ dinv) {
    int i = blockIdx.x * 256 + threadIdx.x;
    if (i < NNODES) {
        rowptr[i] += boff[blockIdx.x];
        dinv[i] = rsqrtf((float)(1 + cnt[i]));  // +1 self-loop
    }
    if (i == 0) rowptr[NNODES] = NEDGES;
}

__global__ void fill_csr(const int* __restrict__ ei, const int* __restrict__ rowptr,
                         int* __restrict__ cursor, int* __restrict__ csrc) {
    int e = blockIdx.x * 256 + threadIdx.x;
    if (e < NEDGES) {
        int s = ei[e];
        int d = ei[NEDGES + e];
        int pos = rowptr[d] + atomicAdd(&cursor[d], 1);
        csrc[pos] = s;
    }
}

// ---- GEMM: C[M,N]=A[M,K]@B[K,N], Bt=[N,K]; 64x128 tile, single-buffer ----
// Small tile => grid 2x larger => ~2-3x resident waves/CU for latency hiding.
#define BM 64
#define BN 128
#define BK 32
#define LDSS 40   // padded row stride (shorts)

__global__ __launch_bounds__(256, 4) void gemm_bf16_tn(
    const void* __restrict__ Araw, const int* __restrict__ dflag, int use_flag,
    const unsigned short* __restrict__ Bt, const unsigned short* __restrict__ bias,
    unsigned short* __restrict__ C, int M, int N, int K)
{
    __shared__ unsigned short As[BM * LDSS];
    __shared__ unsigned short Bs[BN * LDSS];
    const int a_fp32 = use_flag ? dflag[0] : 0;
    const int m0 = blockIdx.x * BM;
    const int n0 = blockIdx.y * BN;
    const int t = threadIdx.x;
    const int wave = t >> 6, lane = t & 63;
    const int quad = lane >> 4, l16 = lane & 15;
    const int wm = (wave >> 1) << 5;   // 0 or 32
    const int wn = (wave & 1) << 6;    // 0 or 64
    const int arow = t >> 2;           // 0..63
    const int cg = t & 3;              // 8-short column group

    f32x4 acc[2][4];
#pragma unroll
    for (int i = 0; i < 2; i++)
#pragma unroll
        for (int j = 0; j < 4; j++) acc[i][j] = (f32x4){0.f, 0.f, 0.f, 0.f};

    for (int k0 = 0; k0 < K; k0 += BK) {
        // ---- stage A (64x32) ----
        const int gm = m0 + arow;
        uint4 av = make_uint4(0u, 0u, 0u, 0u);
        if (gm < M) {
            if (a_fp32) {
                const float* Af = (const float*)Araw + (size_t)gm * K + k0 + cg * 8;
                float4 f0 = *(const float4*)Af;
                float4 f1 = *(const float4*)(Af + 4);
                av.x = (unsigned)f2bf(f0.x) | ((unsigned)f2bf(f0.y) << 16);
                av.y = (unsigned)f2bf(f0.z) | ((unsigned)f2bf(f0.w) << 16);
                av.z = (unsigned)f2bf(f1.x) | ((unsigned)f2bf(f1.y) << 16);
                av.w = (unsigned)f2bf(f1.z) | ((unsigned)f2bf(f1.w) << 16);
            } else {
                av = *(const uint4*)((const unsigned short*)Araw + (size_t)gm * K + k0 + cg * 8);
            }
        }
        *(uint4*)(&As[arow * LDSS + cg * 8]) = av;
        // ---- stage B (128x32), two rows per thread ----
#pragma unroll
        for (int p = 0; p < 2; ++p) {
            const int row = arow + p * 64;
            const int gn = n0 + row;  // N==256: always in range
            uint4 bv = *(const uint4*)(Bt + (size_t)gn * K + k0 + cg * 8);
            *(uint4*)(&Bs[row * LDSS + cg * 8]) = bv;
        }
        __syncthreads();
        bf16x8 af[2], bfv[4];
#pragma unroll
        for (int i = 0; i < 2; i++)
            af[i] = *(const bf16x8*)(&As[(wm + 16 * i + l16) * LDSS + quad * 8]);
#pragma unroll
        for (int j = 0; j < 4; j++)
            bfv[j] = *(const bf16x8*)(&Bs[(wn + 16 * j + l16) * LDSS + quad * 8]);
#pragma unroll
        for (int i = 0; i < 2; i++)
#pragma unroll
            for (int j = 0; j < 4; j++)
                acc[i][j] = __builtin_amdgcn_mfma_f32_16x16x32_bf16(af[i], bfv[j], acc[i][j], 0, 0, 0);
        __syncthreads();
    }
#pragma unroll
    for (int i = 0; i < 2; i++) {
#pragma unroll
        for (int j = 0; j < 4; j++) {
            int gc = n0 + wn + 16 * j + l16;
            float bv = bias ? bf2f(bias[gc]) : 0.f;
#pragma unroll
            for (int r = 0; r < 4; r++) {
                int gr = m0 + wm + 16 * i + quad * 4 + r;
                if (gr < M) C[(size_t)gr * N + gc] = f2bf(acc[i][j][r] + bv);
            }
        }
    }
}

// ------- fused: CSR gather + self-loop + bias + residual + ReLU + LayerNorm -------
// 2 nodes per wave; 1-deep neighbor lookahead to hide L2 gather latency.
__global__ __launch_bounds__(256) void aggregate_ln(
    const int* __restrict__ rowptr, const int* __restrict__ csrc,
    const float* __restrict__ dinv, const unsigned short* __restrict__ m,
    const unsigned short* __restrict__ convB,
    const unsigned short* __restrict__ lnG, const unsigned short* __restrict__ lnB,
    unsigned short* __restrict__ h)
{
    const int half = threadIdx.x >> 5;
    const int lane = threadIdx.x & 31;
    const int node = blockIdx.x * 8 + half;  // NNODES % 8 == 0
    const float di = dinv[node];
    const size_t base = (size_t)node * DH + lane * 8;

    float v[8];
    unpack8(*(const uint4*)(m + base), v);
    const float selfn = di * di;
#pragma unroll
    for (int j = 0; j < 8; j++) v[j] *= selfn;

    const int kb = rowptr[node], ke = rowptr[node + 1];
    int k = kb;
    uint4 cur = make_uint4(0u, 0u, 0u, 0u);
    float nrmC = 0.f;
    if (k < ke) {
        int s = csrc[k];
        cur = *(const uint4*)(m + (size_t)s * DH + lane * 8);
        nrmC = dinv[s] * di;
    }
    while (k < ke) {
        const int kn = k + 1;
        uint4 nxt = make_uint4(0u, 0u, 0u, 0u);
        float nrmN = 0.f;
        if (kn < ke) {
            int s = csrc[kn];
            nxt = *(const uint4*)(m + (size_t)s * DH + lane * 8);
            nrmN = dinv[s] * di;
        }
        float mv[8];
        unpack8(cur, mv);
#pragma unroll
        for (int j = 0; j < 8; j++) v[j] += mv[j] * nrmC;
        cur = nxt; nrmC = nrmN; k = kn;
    }

    float hv[8], cv[8];
    unpack8(*(const uint4*)(h + base), hv);
    unpack8(*(const uint4*)(convB + lane * 8), cv);
    float s1 = 0.f, s2 = 0.f;
#pragma unroll
    for (int j = 0; j < 8; j++) {
        v[j] = fmaxf(v[j] + cv[j] + hv[j], 0.f);
        s1 += v[j];
        s2 += v[j] * v[j];
    }
#pragma unroll
    for (int off = 16; off > 0; off >>= 1) {
        s1 += __shfl_xor(s1, off, 32);
        s2 += __shfl_xor(s2, off, 32);
    }
    const float mu = s1 * (1.f / 256.f);
    const float var = s2 * (1.f / 256.f) - mu * mu;
    const float rs = rsqrtf(var + 1e-5f);
    float gv[8], bv[8];
    unpack8(*(const uint4*)(lnG + lane * 8), gv);
    unpack8(*(const uint4*)(lnB + lane * 8), bv);
    unsigned short o[8];
#pragma unroll
    for (int j = 0; j < 8; j++) o[j] = f2bf((v[j] - mu) * rs * gv[j] + bv[j]);
    uint4 outp;
    outp.x = (unsigned)o[0] | ((unsigned)o[1] << 16);
    outp.y = (unsigned)o[2] | ((unsigned)o[3] << 16);
    outp.z = (unsigned)o[4] | ((unsigned)o[5] << 16);
    outp.w = (unsigned)o[6] | ((unsigned)o[7] << 16);
    *(uint4*)(h + base) = outp;
}

// ---------------- pooling: batch sorted -> boundary detection, no atomics ----------------
__global__ void find_bounds(const int* __restrict__ batch, int* __restrict__ s) {
    int i = blockIdx.x * 256 + threadIdx.x;
    if (i >= NNODES) return;
    int b = batch[i];
    int bp = (i == 0) ? -1 : batch[i - 1];
    for (int g = bp + 1; g <= b; ++g) s[g] = i;
    if (i == NNODES - 1)
        for (int g = b + 1; g <= NGRAPHS; ++g) s[g] = NNODES;
}

#define PSPLIT 8
__global__ __launch_bounds__(256) void pool_partial(
    const unsigned short* __restrict__ h, const int* __restrict__ s,
    float* __restrict__ pg)
{
    const int b = blockIdx.x >> 3, split = blockIdx.x & 7, f = threadIdx.x;
    const int i0 = s[b], i1 = s[b + 1];
    const int len = i1 - i0;
    const int c0 = i0 + (int)(((long)len * split) >> 3);
    const int c1 = i0 + (int)(((long)len * (split + 1)) >> 3);
    float mx = -INFINITY;
    for (int i = c0; i < c1; ++i) mx = fmaxf(mx, bf2f(h[(size_t)i * DH + f]));
    pg[(size_t)blockIdx.x * DH + f] = mx;
}
__global__ __launch_bounds__(256) void pool_reduce(const float* __restrict__ pg,
                                                   float* __restrict__ g) {
    const int b = blockIdx.x, f = threadIdx.x;
    float mx = -INFINITY;
#pragma unroll
    for (int j = 0; j < PSPLIT; ++j) mx = fmaxf(mx, pg[(size_t)(b * PSPLIT + j) * DH + f]);
    g[b * DH + f] = mx;
}

// ---------------- classifier: out = relu(g@W1+b1)@W2+b2 ----------------
__global__ __launch_bounds__(256) void classifier(
    const float* __restrict__ g, const unsigned short* __restrict__ W1,
    const unsigned short* __restrict__ b1, const unsigned short* __restrict__ W2,
    const unsigned short* __restrict__ b2, void* __restrict__ outv,
    const int* __restrict__ flag)
{
    __shared__ float gz[DH];
    __shared__ float zz[DH];
    const int b = blockIdx.x, t = threadIdx.x;
    gz[t] = g[b * DH + t];
    __syncthreads();
    float s = bf2f(b1[t]);
    for (int k = 0; k < DH; ++k) s += gz[k] * bf2f(W1[k * DH + t]);
    zz[t] = fmaxf(s, 0.f);
    __syncthreads();
    if (t < NCLS) {
        float s2 = bf2f(b2[t]);
        for (int k = 0; k < DH; ++k) s2 += zz[k] * bf2f(W2[k * NCLS + t]);
        if (flag[0]) ((float*)outv)[b * NCLS + t] = s2;
        else ((unsigned short*)outv)[b * NCLS + t] = f2bf(s2);
    }
}

extern "C" void kernel_launch(void* const* d_in, const int* in_sizes, int n_in,
                              void* d_out, int out_size, void* d_ws, size_t ws_size,
                              hipStream_t stream)
{
    const void* x      = d_in[0];
    const int* ei      = (const int*)d_in[1];
    const int* batch   = (const int*)d_in[2];
    const void* Win    = d_in[3];
    const void* b_in   = d_in[4];
    const void* convW  = d_in[5];
    const void* convB  = d_in[6];
    const void* lnG    = d_in[7];
    const void* lnB    = d_in[8];
    const void* W1     = d_in[9];
    const void* b1     = d_in[10];
    const void* W2     = d_in[11];
    const void* b2     = d_in[12];

    // workspace layout (bytes), 16B aligned
    char* ws = (char*)d_ws;
    unsigned short* h   = (unsigned short*)(ws + 0);          // 25,600,000
    unsigned short* m   = (unsigned short*)(ws + 25600000);   // 25,600,000
    int* csrc           = (int*)(ws + 51200000);              //  3,200,000
    int* rowptr         = (int*)(ws + 54400000);              //    200,016
    int* cnt            = (int*)(ws + 54600016);              //    200,000
    int* cursor         = (int*)(ws + 54800016);              //    200,000
    float* dinv         = (float*)(ws + 55000016);            //    200,000
    unsigned short* cw  = (unsigned short*)(ws + 55200016);   //    138,768
    unsigned short* WinT= (unsigned short*)(ws + 55338784);   //    393,216
    unsigned short* WcT = (unsigned short*)(ws + 55732000);   //    393,216
    float* g            = (float*)(ws + 56125216);            //     65,536
    float* pg           = (float*)(ws + 56190752);            //    524,288
    int* gb             = (int*)(ws + 56715040);              //        272
    int* bsum           = (int*)(ws + 56715312);              //        800
    int* boff           = (int*)(ws + 56716112);              //        800
    int* flag           = (int*)(ws + 56716912);              //         16
    const size_t NEED   = 56716928;
    if (ws_size < NEED) {
        fill_sentinel<<<(out_size / 2 + 255) / 256, 256, 0, stream>>>((float*)d_out, out_size / 2);
        return;
    }

    // canonical small weights (bf16 element offsets within cw)
    unsigned short* cBin   = cw + 0;
    unsigned short* cConvB = cw + 256;
    unsigned short* cLnG   = cw + 1024;
    unsigned short* cLnB   = cw + 1792;
    unsigned short* cW1    = cw + 2560;
    unsigned short* cW2    = cw + 68096;
    unsigned short* cB1    = cw + 69120;
    unsigned short* cB2    = cw + 69376;

    detect_dtype<<<1, 256, 0, stream>>>((const unsigned short*)x, flag);

    // ---- CSR build (dst-sorted) + degrees ----
    hipMemsetAsync(cnt, 0, 400000, stream);  // cnt AND cursor (contiguous)
    count_edges<<<(NEDGES + 255) / 256, 256, 0, stream>>>(ei, cnt);
    scan_local<<<SCAN_BLOCKS, 256, 0, stream>>>(cnt, rowptr, bsum);
    scan_bsum<<<1, 256, 0, stream>>>(bsum, boff);
    scan_finish<<<SCAN_BLOCKS, 256, 0, stream>>>(rowptr, boff, cnt, dinv);
    fill_csr<<<(NEDGES + 255) / 256, 256, 0, stream>>>(ei, rowptr, cursor, csrc);

    // ---- weights: canon + convert/transpose ----
    canon_small<<<(69380 + 255) / 256, 256, 0, stream>>>(b_in, convB, lnG, lnB, W1, W2, b1, b2, cw, flag);
    transpose_win<<<(DIN * DH + 255) / 256, 256, 0, stream>>>(Win, WinT, flag);
    transpose_convw<<<(3 * DH * DH + 255) / 256, 256, 0, stream>>>(convW, WcT, flag);

    // ---- h = x @ W_in + b_in ----
    dim3 gg((NNODES + BM - 1) / BM, DH / BN);
    gemm_bf16_tn<<<gg, 256, 0, stream>>>(x, flag, 1, WinT, cBin, h, NNODES, DH, DIN);

    // ---- 3 GCN layers ----
    for (int i = 0; i < 3; i++) {
        gemm_bf16_tn<<<gg, 256, 0, stream>>>(h, flag, 0, WcT + i * DH * DH, nullptr, m,
                                             NNODES, DH, DH);
        aggregate_ln<<<NNODES / 8, 256, 0, stream>>>(
            rowptr, csrc, dinv, m, cConvB + i * DH, cLnG + i * DH, cLnB + i * DH, h);
    }

    // ---- global max pool + classifier ----
    find_bounds<<<(NNODES + 255) / 256, 256, 0, stream>>>(batch, gb);
    pool_partial<<<NGRAPHS * PSPLIT, 256, 0, stream>>>(h, gb, pg);
    pool_reduce<<<NGRAPHS, 256, 0, stream>>>(pg, g);
    classifier<<<NGRAPHS, 256, 0, stream>>>(g, cW1, cB1, cW2, cB2, d_out, flag);
}

// Round 7
// 676.322 us; speedup vs baseline: 1.1858x; 1.0431x over previous
//
#include <hip/hip_runtime.h>
#include <hip/hip_bf16.h>
#include <math.h>

#define NNODES 50000
#define NEDGES 800000
#define DIN 768
#define DH 256
#define NCLS 4
#define NGRAPHS 64
#define SCAN_BLOCKS 196   // ceil(NNODES/256)

typedef __bf16 bf16x8 __attribute__((ext_vector_type(8)));
typedef float f32x4 __attribute__((ext_vector_type(4)));

static __device__ __forceinline__ float bf2f(unsigned short u) {
    union { unsigned u32; float f; } v; v.u32 = ((unsigned)u) << 16; return v.f;
}
static __device__ __forceinline__ unsigned short f2bf(float f) {
    union { float f; unsigned u; } v; v.f = f;
    unsigned r = (v.u + 0x7fffu + ((v.u >> 16) & 1u)) >> 16;
    return (unsigned short)r;
}
static __device__ __forceinline__ void unpack8(uint4 u, float* f) {
    f[0] = bf2f((unsigned short)(u.x & 0xffff)); f[1] = bf2f((unsigned short)(u.x >> 16));
    f[2] = bf2f((unsigned short)(u.y & 0xffff)); f[3] = bf2f((unsigned short)(u.y >> 16));
    f[4] = bf2f((unsigned short)(u.z & 0xffff)); f[5] = bf2f((unsigned short)(u.z >> 16));
    f[6] = bf2f((unsigned short)(u.w & 0xffff)); f[7] = bf2f((unsigned short)(u.w >> 16));
}

// ---------------- dtype detection (fp32 vs bf16 inputs) ----------------
__global__ void detect_dtype(const unsigned short* __restrict__ x, int* __restrict__ flag) {
    __shared__ int cnt_s;
    if (threadIdx.x == 0) cnt_s = 0;
    __syncthreads();
    int c = 0;
    for (int i = 0; i < 16; ++i) {
        float v = bf2f(x[threadIdx.x * 16 + i]);
        if (!(fabsf(v) < 1e10f)) c++;
    }
    atomicAdd(&cnt_s, c);
    __syncthreads();
    if (threadIdx.x == 0) flag[0] = (cnt_s > 32) ? 1 : 0;  // 1 => fp32
}

static __device__ __forceinline__ unsigned short cload(const void* src, int i, int fp32) {
    return fp32 ? f2bf(((const float*)src)[i]) : ((const unsigned short*)src)[i];
}

// ---------------- fused small-weight canonicalization ----------------
__global__ void canon_small(const void* b_in, const void* convB, const void* lnG,
                            const void* lnB, const void* W1, const void* W2,
                            const void* b1, const void* b2,
                            unsigned short* __restrict__ dst, const int* __restrict__ flag) {
    int i = blockIdx.x * 256 + threadIdx.x;
    if (i >= 69380) return;
    const int fp32 = flag[0];
    int j = i;
    if (j < 256)  { dst[i] = cload(b_in, j, fp32); return; }  j -= 256;
    if (j < 768)  { dst[i] = cload(convB, j, fp32); return; } j -= 768;
    if (j < 768)  { dst[i] = cload(lnG, j, fp32); return; }   j -= 768;
    if (j < 768)  { dst[i] = cload(lnB, j, fp32); return; }   j -= 768;
    if (j < 65536){ dst[i] = cload(W1, j, fp32); return; }    j -= 65536;
    if (j < 1024) { dst[i] = cload(W2, j, fp32); return; }    j -= 1024;
    if (j < 256)  { dst[i] = cload(b1, j, fp32); return; }    j -= 256;
    dst[i] = cload(b2, j, fp32);
}

// ---------------- fused convert+transpose for GEMM B operands ----------------
__global__ void transpose_win(const void* __restrict__ src, unsigned short* __restrict__ dst,
                              const int* __restrict__ flag) {
    int idx = blockIdx.x * 256 + threadIdx.x;
    if (idx < DIN * DH) {
        int r = idx / DH, c = idx % DH;
        dst[(size_t)c * DIN + r] = cload(src, idx, flag[0]);
    }
}
__global__ void transpose_convw(const void* __restrict__ src, unsigned short* __restrict__ dst,
                                const int* __restrict__ flag) {
    int idx = blockIdx.x * 256 + threadIdx.x;
    if (idx < 3 * DH * DH) {
        int l = idx >> 16, rc = idx & 65535;
        int r = rc >> 8, c = rc & 255;
        dst[(l << 16) + c * DH + r] = cload(src, idx, flag[0]);
    }
}

// ---------------- diagnostic sentinel (ws too small) ----------------
__global__ void fill_sentinel(float* out, int n) {
    int i = blockIdx.x * 256 + threadIdx.x;
    if (i < n) out[i] = 1000.0f;
}

// ---------------- CSR build ----------------
__global__ void count_edges(const int* __restrict__ ei, int* __restrict__ cnt) {
    int e = blockIdx.x * 256 + threadIdx.x;
    if (e < NEDGES) atomicAdd(&cnt[ei[NEDGES + e]], 1);
}

__global__ void scan_local(const int* __restrict__ cnt, int* __restrict__ rowptr,
                           int* __restrict__ bsum) {
    __shared__ int tmp[256];
    int i = blockIdx.x * 256 + threadIdx.x;
    int v = (i < NNODES) ? cnt[i] : 0;
    tmp[threadIdx.x] = v;
    __syncthreads();
    for (int off = 1; off < 256; off <<= 1) {
        int a = (threadIdx.x >= off) ? tmp[threadIdx.x - off] : 0;
        __syncthreads();
        tmp[threadIdx.x] += a;
        __syncthreads();
    }
    if (i < NNODES) rowptr[i] = tmp[threadIdx.x] - v;  // local exclusive
    if (threadIdx.x == 255) bsum[blockIdx.x] = tmp[255];
}
__global__ void scan_bsum(const int* __restrict__ bsum, int* __restrict__ boff) {
    __shared__ int tmp[256];
    int t = threadIdx.x;
    int v = (t < SCAN_BLOCKS) ? bsum[t] : 0;
    tmp[t] = v;
    __syncthreads();
    for (int off = 1; off < 256; off <<= 1) {
        int a = (t >= off) ? tmp[t - off] : 0;
        __syncthreads();
        tmp[t] += a;
        __syncthreads();
    }
    if (t < SCAN_BLOCKS) boff[t] = tmp[t] - v;
}
__global__ void scan_finish(int* __restrict__ rowptr, const int* __restrict__ boff,
                            const int* __restrict__ cnt, float* __restrict__ dinv) {
    int i = blockIdx.x * 256 + threadIdx.x;
    if (i < NNODES) {
        rowptr[i] += boff[blockIdx.x];
        dinv[i] = rsqrtf((float)(1 + cnt[i]));  // +1 self-loop
    }
    if (i == 0) rowptr[NNODES] = NEDGES;
}

__global__ void fill_csr(const int* __restrict__ ei, const int* __restrict__ rowptr,
                         int* __restrict__ cursor, int* __restrict__ csrc) {
    int e = blockIdx.x * 256 + threadIdx.x;
    if (e < NEDGES) {
        int s = ei[e];
        int d = ei[NEDGES + e];
        int pos = rowptr[d] + atomicAdd(&cursor[d], 1);
        csrc[pos] = s;
    }
}

// ---- GEMM: C[M,N]=A[M,K]@B[K,N], Bt=[N,K]; 64x128 tile, single-buffer ----
// (frozen from R6: occupancy 53%, 105 us for K=768)
#define BM 64
#define BN 128
#define BK 32
#define LDSS 40   // padded row stride (shorts)

__global__ __launch_bounds__(256, 4) void gemm_bf16_tn(
    const void* __restrict__ Araw, const int* __restrict__ dflag, int use_flag,
    const unsigned short* __restrict__ Bt, const unsigned short* __restrict__ bias,
    unsigned short* __restrict__ C, int M, int N, int K)
{
    __shared__ unsigned short As[BM * LDSS];
    __shared__ unsigned short Bs[BN * LDSS];
    const int a_fp32 = use_flag ? dflag[0] : 0;
    const int m0 = blockIdx.x * BM;
    const int n0 = blockIdx.y * BN;
    const int t = threadIdx.x;
    const int wave = t >> 6, lane = t & 63;
    const int quad = lane >> 4, l16 = lane & 15;
    const int wm = (wave >> 1) << 5;   // 0 or 32
    const int wn = (wave & 1) << 6;    // 0 or 64
    const int arow = t >> 2;           // 0..63
    const int cg = t & 3;              // 8-short column group

    f32x4 acc[2][4];
#pragma unroll
    for (int i = 0; i < 2; i++)
#pragma unroll
        for (int j = 0; j < 4; j++) acc[i][j] = (f32x4){0.f, 0.f, 0.f, 0.f};

    for (int k0 = 0; k0 < K; k0 += BK) {
        const int gm = m0 + arow;
        uint4 av = make_uint4(0u, 0u, 0u, 0u);
        if (gm < M) {
            if (a_fp32) {
                const float* Af = (const float*)Araw + (size_t)gm * K + k0 + cg * 8;
                float4 f0 = *(const float4*)Af;
                float4 f1 = *(const float4*)(Af + 4);
                av.x = (unsigned)f2bf(f0.x) | ((unsigned)f2bf(f0.y) << 16);
                av.y = (unsigned)f2bf(f0.z) | ((unsigned)f2bf(f0.w) << 16);
                av.z = (unsigned)f2bf(f1.x) | ((unsigned)f2bf(f1.y) << 16);
                av.w = (unsigned)f2bf(f1.z) | ((unsigned)f2bf(f1.w) << 16);
            } else {
                av = *(const uint4*)((const unsigned short*)Araw + (size_t)gm * K + k0 + cg * 8);
            }
        }
        *(uint4*)(&As[arow * LDSS + cg * 8]) = av;
#pragma unroll
        for (int p = 0; p < 2; ++p) {
            const int row = arow + p * 64;
            const int gn = n0 + row;  // N==256: always in range
            uint4 bv = *(const uint4*)(Bt + (size_t)gn * K + k0 + cg * 8);
            *(uint4*)(&Bs[row * LDSS + cg * 8]) = bv;
        }
        __syncthreads();
        bf16x8 af[2], bfv[4];
#pragma unroll
        for (int i = 0; i < 2; i++)
            af[i] = *(const bf16x8*)(&As[(wm + 16 * i + l16) * LDSS + quad * 8]);
#pragma unroll
        for (int j = 0; j < 4; j++)
            bfv[j] = *(const bf16x8*)(&Bs[(wn + 16 * j + l16) * LDSS + quad * 8]);
#pragma unroll
        for (int i = 0; i < 2; i++)
#pragma unroll
            for (int j = 0; j < 4; j++)
                acc[i][j] = __builtin_amdgcn_mfma_f32_16x16x32_bf16(af[i], bfv[j], acc[i][j], 0, 0, 0);
        __syncthreads();
    }
#pragma unroll
    for (int i = 0; i < 2; i++) {
#pragma unroll
        for (int j = 0; j < 4; j++) {
            int gc = n0 + wn + 16 * j + l16;
            float bv = bias ? bf2f(bias[gc]) : 0.f;
#pragma unroll
            for (int r = 0; r < 4; r++) {
                int gr = m0 + wm + 16 * i + quad * 4 + r;
                if (gr < M) C[(size_t)gr * N + gc] = f2bf(acc[i][j][r] + bv);
            }
        }
    }
}

// ------- fused: CSR gather + self-loop + bias + residual + ReLU + LayerNorm -------
// 2 nodes per wave (32 lanes each, 16 B/lane). Neighbor loop runs 4 independent
// accumulator streams -> 4 row-gathers in flight (MLP), no serial dependency.
__global__ __launch_bounds__(256) void aggregate_ln(
    const int* __restrict__ rowptr, const int* __restrict__ csrc,
    const float* __restrict__ dinv, const unsigned short* __restrict__ m,
    const unsigned short* __restrict__ convB,
    const unsigned short* __restrict__ lnG, const unsigned short* __restrict__ lnB,
    unsigned short* __restrict__ h)
{
    const int half = threadIdx.x >> 5;
    const int lane = threadIdx.x & 31;
    const int node = blockIdx.x * 8 + half;  // NNODES % 8 == 0
    const float di = dinv[node];
    const size_t base = (size_t)node * DH + lane * 8;
    const size_t lo = lane * 8;

    float v0[8], v1[8], v2[8], v3[8];
    unpack8(*(const uint4*)(m + base), v0);
    const float selfn = di * di;
#pragma unroll
    for (int j = 0; j < 8; j++) { v0[j] *= selfn; v1[j] = 0.f; v2[j] = 0.f; v3[j] = 0.f; }

    const int kb = rowptr[node], ke = rowptr[node + 1];
    int k = kb;
    for (; k + 4 <= ke; k += 4) {
        const int s0 = csrc[k], s1 = csrc[k + 1], s2 = csrc[k + 2], s3 = csrc[k + 3];
        const uint4 r0 = *(const uint4*)(m + (size_t)s0 * DH + lo);
        const uint4 r1 = *(const uint4*)(m + (size_t)s1 * DH + lo);
        const uint4 r2 = *(const uint4*)(m + (size_t)s2 * DH + lo);
        const uint4 r3 = *(const uint4*)(m + (size_t)s3 * DH + lo);
        const float n0 = dinv[s0] * di, n1 = dinv[s1] * di;
        const float n2 = dinv[s2] * di, n3 = dinv[s3] * di;
        float t0[8], t1[8], t2[8], t3[8];
        unpack8(r0, t0); unpack8(r1, t1); unpack8(r2, t2); unpack8(r3, t3);
#pragma unroll
        for (int j = 0; j < 8; j++) {
            v0[j] += t0[j] * n0;
            v1[j] += t1[j] * n1;
            v2[j] += t2[j] * n2;
            v3[j] += t3[j] * n3;
        }
    }
    for (; k < ke; ++k) {
        const int s = csrc[k];
        const uint4 r = *(const uint4*)(m + (size_t)s * DH + lo);
        const float n = dinv[s] * di;
        float tv[8];
        unpack8(r, tv);
#pragma unroll
        for (int j = 0; j < 8; j++) v0[j] += tv[j] * n;
    }
#pragma unroll
    for (int j = 0; j < 8; j++) v0[j] += (v1[j] + v2[j]) + v3[j];

    float hv[8], cv[8];
    unpack8(*(const uint4*)(h + base), hv);
    unpack8(*(const uint4*)(convB + lo), cv);
    float s1 = 0.f, s2 = 0.f;
#pragma unroll
    for (int j = 0; j < 8; j++) {
        v0[j] = fmaxf(v0[j] + cv[j] + hv[j], 0.f);
        s1 += v0[j];
        s2 += v0[j] * v0[j];
    }
#pragma unroll
    for (int off = 16; off > 0; off >>= 1) {
        s1 += __shfl_xor(s1, off, 32);
        s2 += __shfl_xor(s2, off, 32);
    }
    const float mu = s1 * (1.f / 256.f);
    const float var = s2 * (1.f / 256.f) - mu * mu;
    const float rs = rsqrtf(var + 1e-5f);
    float gv[8], bv[8];
    unpack8(*(const uint4*)(lnG + lo), gv);
    unpack8(*(const uint4*)(lnB + lo), bv);
    unsigned short o[8];
#pragma unroll
    for (int j = 0; j < 8; j++) o[j] = f2bf((v0[j] - mu) * rs * gv[j] + bv[j]);
    uint4 outp;
    outp.x = (unsigned)o[0] | ((unsigned)o[1] << 16);
    outp.y = (unsigned)o[2] | ((unsigned)o[3] << 16);
    outp.z = (unsigned)o[4] | ((unsigned)o[5] << 16);
    outp.w = (unsigned)o[6] | ((unsigned)o[7] << 16);
    *(uint4*)(h + base) = outp;
}

// ---------------- pooling: batch sorted -> boundary detection, no atomics ----------------
__global__ void find_bounds(const int* __restrict__ batch, int* __restrict__ s) {
    int i = blockIdx.x * 256 + threadIdx.x;
    if (i >= NNODES) return;
    int b = batch[i];
    int bp = (i == 0) ? -1 : batch[i - 1];
    for (int g = bp + 1; g <= b; ++g) s[g] = i;
    if (i == NNODES - 1)
        for (int g = b + 1; g <= NGRAPHS; ++g) s[g] = NNODES;
}

#define PSPLIT 8
__global__ __launch_bounds__(256) void pool_partial(
    const unsigned short* __restrict__ h, const int* __restrict__ s,
    float* __restrict__ pg)
{
    const int b = blockIdx.x >> 3, split = blockIdx.x & 7, f = threadIdx.x;
    const int i0 = s[b], i1 = s[b + 1];
    const int len = i1 - i0;
    const int c0 = i0 + (int)(((long)len * split) >> 3);
    const int c1 = i0 + (int)(((long)len * (split + 1)) >> 3);
    float mx = -INFINITY;
    for (int i = c0; i < c1; ++i) mx = fmaxf(mx, bf2f(h[(size_t)i * DH + f]));
    pg[(size_t)blockIdx.x * DH + f] = mx;
}
__global__ __launch_bounds__(256) void pool_reduce(const float* __restrict__ pg,
                                                   float* __restrict__ g) {
    const int b = blockIdx.x, f = threadIdx.x;
    float mx = -INFINITY;
#pragma unroll
    for (int j = 0; j < PSPLIT; ++j) mx = fmaxf(mx, pg[(size_t)(b * PSPLIT + j) * DH + f]);
    g[b * DH + f] = mx;
}

// ---------------- classifier: out = relu(g@W1+b1)@W2+b2 ----------------
__global__ __launch_bounds__(256) void classifier(
    const float* __restrict__ g, const unsigned short* __restrict__ W1,
    const unsigned short* __restrict__ b1, const unsigned short* __restrict__ W2,
    const unsigned short* __restrict__ b2, void* __restrict__ outv,
    const int* __restrict__ flag)
{
    __shared__ float gz[DH];
    __shared__ float zz[DH];
    const int b = blockIdx.x, t = threadIdx.x;
    gz[t] = g[b * DH + t];
    __syncthreads();
    float s = bf2f(b1[t]);
    for (int k = 0; k < DH; ++k) s += gz[k] * bf2f(W1[k * DH + t]);
    zz[t] = fmaxf(s, 0.f);
    __syncthreads();
    if (t < NCLS) {
        float s2 = bf2f(b2[t]);
        for (int k = 0; k < DH; ++k) s2 += zz[k] * bf2f(W2[k * NCLS + t]);
        if (flag[0]) ((float*)outv)[b * NCLS + t] = s2;
        else ((unsigned short*)outv)[b * NCLS + t] = f2bf(s2);
    }
}

extern "C" void kernel_launch(void* const* d_in, const int* in_sizes, int n_in,
                              void* d_out, int out_size, void* d_ws, size_t ws_size,
                              hipStream_t stream)
{
    const void* x      = d_in[0];
    const int* ei      = (const int*)d_in[1];
    const int* batch   = (const int*)d_in[2];
    const void* Win    = d_in[3];
    const void* b_in   = d_in[4];
    const void* convW  = d_in[5];
    const void* convB  = d_in[6];
    const void* lnG    = d_in[7];
    const void* lnB    = d_in[8];
    const void* W1     = d_in[9];
    const void* b1     = d_in[10];
    const void* W2     = d_in[11];
    const void* b2     = d_in[12];

    // workspace layout (bytes), 16B aligned
    char* ws = (char*)d_ws;
    unsigned short* h   = (unsigned short*)(ws + 0);          // 25,600,000
    unsigned short* m   = (unsigned short*)(ws + 25600000);   // 25,600,000
    int* csrc           = (int*)(ws + 51200000);              //  3,200,000
    int* rowptr         = (int*)(ws + 54400000);              //    200,016
    int* cnt            = (int*)(ws + 54600016);              //    200,000
    int* cursor         = (int*)(ws + 54800016);              //    200,000
    float* dinv         = (float*)(ws + 55000016);            //    200,000
    unsigned short* cw  = (unsigned short*)(ws + 55200016);   //    138,768
    unsigned short* WinT= (unsigned short*)(ws + 55338784);   //    393,216
    unsigned short* WcT = (unsigned short*)(ws + 55732000);   //    393,216
    float* g            = (float*)(ws + 56125216);            //     65,536
    float* pg           = (float*)(ws + 56190752);            //    524,288
    int* gb             = (int*)(ws + 56715040);              //        272
    int* bsum           = (int*)(ws + 56715312);              //        800
    int* boff           = (int*)(ws + 56716112);              //        800
    int* flag           = (int*)(ws + 56716912);              //         16
    const size_t NEED   = 56716928;
    if (ws_size < NEED) {
        fill_sentinel<<<(out_size / 2 + 255) / 256, 256, 0, stream>>>((float*)d_out, out_size / 2);
        return;
    }

    // canonical small weights (bf16 element offsets within cw)
    unsigned short* cBin   = cw + 0;
    unsigned short* cConvB = cw + 256;
    unsigned short* cLnG   = cw + 1024;
    unsigned short* cLnB   = cw + 1792;
    unsigned short* cW1    = cw + 2560;
    unsigned short* cW2    = cw + 68096;
    unsigned short* cB1    = cw + 69120;
    unsigned short* cB2    = cw + 69376;

    detect_dtype<<<1, 256, 0, stream>>>((const unsigned short*)x, flag);

    // ---- CSR build (dst-sorted) + degrees ----
    hipMemsetAsync(cnt, 0, 400000, stream);  // cnt AND cursor (contiguous)
    count_edges<<<(NEDGES + 255) / 256, 256, 0, stream>>>(ei, cnt);
    scan_local<<<SCAN_BLOCKS, 256, 0, stream>>>(cnt, rowptr, bsum);
    scan_bsum<<<1, 256, 0, stream>>>(bsum, boff);
    scan_finish<<<SCAN_BLOCKS, 256, 0, stream>>>(rowptr, boff, cnt, dinv);
    fill_csr<<<(NEDGES + 255) / 256, 256, 0, stream>>>(ei, rowptr, cursor, csrc);

    // ---- weights: canon + convert/transpose ----
    canon_small<<<(69380 + 255) / 256, 256, 0, stream>>>(b_in, convB, lnG, lnB, W1, W2, b1, b2, cw, flag);
    transpose_win<<<(DIN * DH + 255) / 256, 256, 0, stream>>>(Win, WinT, flag);
    transpose_convw<<<(3 * DH * DH + 255) / 256, 256, 0, stream>>>(convW, WcT, flag);

    // ---- h = x @ W_in + b_in ----
    dim3 gg((NNODES + BM - 1) / BM, DH / BN);
    gemm_bf16_tn<<<gg, 256, 0, stream>>>(x, flag, 1, WinT, cBin, h, NNODES, DH, DIN);

    // ---- 3 GCN layers ----
    for (int i = 0; i < 3; i++) {
        gemm_bf16_tn<<<gg, 256, 0, stream>>>(h, flag, 0, WcT + i * DH * DH, nullptr, m,
                                             NNODES, DH, DH);
        aggregate_ln<<<NNODES / 8, 256, 0, stream>>>(
            rowptr, csrc, dinv, m, cConvB + i * DH, cLnG + i * DH, cLnB + i * DH, h);
    }

    // ---- global max pool + classifier ----
    find_bounds<<<(NNODES + 255) / 256, 256, 0, stream>>>(batch, gb);
    pool_partial<<<NGRAPHS * PSPLIT, 256, 0, stream>>>(h, gb, pg);
    pool_reduce<<<NGRAPHS, 256, 0, stream>>>(pg, g);
    classifier<<<NGRAPHS, 256, 0, stream>>>(g, cW1, cB1, cW2, cB2, d_out, flag);
}